// Round 3
// 190.793 us; speedup vs baseline: 1.0117x; 1.0117x over previous
//
#include <hip/hip_runtime.h>

typedef unsigned short u16;
typedef unsigned int u32;
typedef float v4f __attribute__((ext_vector_type(4)));
typedef __bf16 bf16x8 __attribute__((ext_vector_type(8)));

#define BATCH 8
#define CDIM 768
#define NHEAD 12
#define DH 64
#define NSEQ 1024
#define SCL 0.18033688011112042f

__device__ __forceinline__ u16 f2bf(float f) {
  u32 u = __builtin_bit_cast(u32, f);
  u += 0x7fffu + ((u >> 16) & 1u);   // RNE
  return (u16)(u >> 16);
}

__device__ __forceinline__ u16 b16(float f) {
  return (u16)((__builtin_bit_cast(u32, f) + 0x8000u) >> 16);
}

__device__ __forceinline__ u32 pkbf(float hi, float lo) {
  u32 a = __builtin_bit_cast(u32, hi) + 0x8000u;
  u32 b = __builtin_bit_cast(u32, lo) + 0x8000u;
  return __builtin_amdgcn_perm(a, b, 0x07060302u);  // {a[31:16], b[31:16]}
}

__device__ __forceinline__ v4f mfma16(bf16x8 a, bf16x8 b, v4f c) {
  return __builtin_amdgcn_mfma_f32_16x16x32_bf16(a, b, c, 0, 0, 0);
}

__device__ __forceinline__ void gload16(const u16* g, u16* l) {
  __builtin_amdgcn_global_load_lds(
      (const __attribute__((address_space(1))) void*)g,
      (__attribute__((address_space(3))) void*)l, 16, 0, 0);
}

// ------------- kernel: fused prep --------------------------------------
__global__ __launch_bounds__(256) void k_prep(const float* __restrict__ x,
                                              const float* __restrict__ wq,
                                              const float* __restrict__ wp,
                                              u16* __restrict__ xT,
                                              u16* __restrict__ wqb,
                                              u16* __restrict__ wpb) {
  __shared__ u16 Ts[64][72];
  int bid = blockIdx.x;
  int t = threadIdx.x;
  if (bid < 2304) {
    bool isQ = bid < 1728;
    const float* s = isQ ? wq : wp;
    u16* d = isQ ? wqb : wpb;
    int i = (isQ ? bid : bid - 1728) * 256 + t;
    float4 v = ((const float4*)s)[i];
    u32 lo = (u32)f2bf(v.x) | ((u32)f2bf(v.y) << 16);
    u32 hi = (u32)f2bf(v.z) | ((u32)f2bf(v.w) << 16);
    ((uint2*)d)[i] = uint2{lo, hi};
    return;
  }
  int id = bid - 2304;
  int p0 = (id & 15) * 64; id >>= 4;
  int c0 = (id % 12) * 64; int b = id / 12;
  int cr = t >> 4;
  int p4 = (t & 15) * 4;
  const float* src = x + ((size_t)b * CDIM + c0) * NSEQ + p0;
#pragma unroll
  for (int i = 0; i < 4; ++i) {
    int c = cr + i * 16;
    float4 v = *(const float4*)&src[(size_t)c * NSEQ + p4];
    Ts[p4 + 0][c] = f2bf(v.x);
    Ts[p4 + 1][c] = f2bf(v.y);
    Ts[p4 + 2][c] = f2bf(v.z);
    Ts[p4 + 3][c] = f2bf(v.w);
  }
  __syncthreads();
  int p = t >> 2;
  int cq = t & 3;
  u16* dst = xT + ((size_t)b * NSEQ + p0 + p) * CDIM + c0;
#pragma unroll
  for (int j = 0; j < 2; ++j) {
    int ch = cq + j * 4;
    *(int4*)&dst[ch * 8] = *(const int4*)&Ts[p][ch * 8];
  }
}

// ------------- 128x256 triple-buffered pipelined GEMM core --------------
// BM=128 BN=256 BK=64, 8 waves (2M x 4N), per-wave 64x64 output, 512 thr.
// LDS: 3 bufs x (A 128x64 + B 256x64) bf16 = 144 KB -> 1 block/CU.
// XOR chunk swizzle: LDS slot (row, pc) holds global k-chunk pc^(row&7),
// via pre-swizzled per-lane GLOBAL source (LDS dest linear); reads apply
// the same XOR. Pipeline: while computing kt, stage kt+2; 6 DMA per tile;
// s_waitcnt vmcnt(6) drains exactly the next tile's group. setprio on MFMA.
#define NKT 12     // CDIM/64

__device__ __forceinline__ void gemm_core(const u16* __restrict__ Ag,
                                          const u16* __restrict__ Bg,
                                          u16* sm, v4f (&acc)[4][4]) {
  int t = threadIdx.x, lane = t & 63, wid = t >> 6;
  int ln = lane & 15, quad = lane >> 4;
  int wm = wid >> 2, wn = wid & 3;

  int sr = t >> 3;                               // 0..63 row within instr
  int sc = ((t & 7) ^ (sr & 7)) * 8;             // swizzled source chunk
  const u16* As0 = Ag + (size_t)sr * CDIM + sc;
  const u16* Bs0 = Bg + (size_t)sr * CDIM + sc;
  int ldw = wid * 512;

  int x = ln & 7;
  int rA = (wm * 64 + ln) * 64;
  int rB = 8192 + (wn * 64 + ln) * 64;
  int c0 = (quad ^ x) * 8;
  int c1 = ((4 + quad) ^ x) * 8;

  // ---- prologue: stage K-tiles 0 and 1 ----
  {
    u16* sb = sm;
    gload16(As0, sb + ldw);
    gload16(As0 + (size_t)64 * CDIM, sb + 4096 + ldw);
    gload16(Bs0, sb + 8192 + ldw);
    gload16(Bs0 + (size_t)64 * CDIM, sb + 12288 + ldw);
    gload16(Bs0 + (size_t)128 * CDIM, sb + 16384 + ldw);
    gload16(Bs0 + (size_t)192 * CDIM, sb + 20480 + ldw);
  }
  asm volatile("" ::: "memory");
  {
    u16* sb = sm + 24576;
    const u16* Ak = As0 + 64;
    const u16* Bk = Bs0 + 64;
    gload16(Ak, sb + ldw);
    gload16(Ak + (size_t)64 * CDIM, sb + 4096 + ldw);
    gload16(Bk, sb + 8192 + ldw);
    gload16(Bk + (size_t)64 * CDIM, sb + 12288 + ldw);
    gload16(Bk + (size_t)128 * CDIM, sb + 16384 + ldw);
    gload16(Bk + (size_t)192 * CDIM, sb + 20480 + ldw);
  }
  asm volatile("s_waitcnt vmcnt(6)" ::: "memory");
  asm volatile("s_barrier" ::: "memory");

#pragma unroll
  for (int kt = 0; kt < NKT; ++kt) {
    const u16* sb = sm + (kt % 3) * 24576;
    u16* nb = sm + ((kt + 2) % 3) * 24576;
    const u16* Ak = As0 + (kt + 2) * 64;
    const u16* Bk = Bs0 + (kt + 2) * 64;

    // ---- phase 0 ----
    bf16x8 af[2][2], bfr[4][2];
#pragma unroll
    for (int m = 0; m < 2; ++m) {
      af[m][0] = *(const bf16x8*)&sb[rA + m * 1024 + c0];
      af[m][1] = *(const bf16x8*)&sb[rA + m * 1024 + c1];
    }
#pragma unroll
    for (int n = 0; n < 4; ++n) {
      bfr[n][0] = *(const bf16x8*)&sb[rB + n * 1024 + c0];
      bfr[n][1] = *(const bf16x8*)&sb[rB + n * 1024 + c1];
    }
    if (kt < NKT - 2) {
      gload16(Ak, nb + ldw);
      gload16(Ak + (size_t)64 * CDIM, nb + 4096 + ldw);
      gload16(Bk, nb + 8192 + ldw);
    }
    asm volatile("s_barrier" ::: "memory");
    asm volatile("s_waitcnt lgkmcnt(0)" ::: "memory");
    __builtin_amdgcn_sched_barrier(0);
    __builtin_amdgcn_s_setprio(1);
#pragma unroll
    for (int m = 0; m < 2; ++m)
#pragma unroll
      for (int n = 0; n < 4; ++n) {
        acc[m][n] = mfma16(af[m][0], bfr[n][0], acc[m][n]);
        acc[m][n] = mfma16(af[m][1], bfr[n][1], acc[m][n]);
      }
    __builtin_amdgcn_s_setprio(0);
    asm volatile("s_barrier" ::: "memory");

    // ---- phase 1 ----
#pragma unroll
    for (int m = 0; m < 2; ++m) {
      af[m][0] = *(const bf16x8*)&sb[rA + (m + 2) * 1024 + c0];
      af[m][1] = *(const bf16x8*)&sb[rA + (m + 2) * 1024 + c1];
    }
    if (kt < NKT - 2) {
      gload16(Bk + (size_t)64 * CDIM, nb + 12288 + ldw);
      gload16(Bk + (size_t)128 * CDIM, nb + 16384 + ldw);
      gload16(Bk + (size_t)192 * CDIM, nb + 20480 + ldw);
      asm volatile("s_waitcnt vmcnt(6)" ::: "memory");
    } else if (kt == NKT - 2) {
      asm volatile("s_waitcnt vmcnt(0)" ::: "memory");
    }
    asm volatile("s_barrier" ::: "memory");
    asm volatile("s_waitcnt lgkmcnt(0)" ::: "memory");
    __builtin_amdgcn_sched_barrier(0);
    __builtin_amdgcn_s_setprio(1);
#pragma unroll
    for (int m = 0; m < 2; ++m)
#pragma unroll
      for (int n = 0; n < 4; ++n) {
        acc[m + 2][n] = mfma16(af[m][0], bfr[n][0], acc[m + 2][n]);
        acc[m + 2][n] = mfma16(af[m][1], bfr[n][1], acc[m + 2][n]);
      }
    __builtin_amdgcn_s_setprio(0);
    asm volatile("s_barrier" ::: "memory");
  }
}

// ------------- kernel: QKV GEMM -----------------------------------------
__global__ __launch_bounds__(512, 2) void k_gemm_qkv(const u16* __restrict__ Wb,
                                                     const u16* __restrict__ xT,
                                                     u16* __restrict__ qkT,
                                                     u16* __restrict__ vbuf) {
  __shared__ u16 sm[3 * 24576];   // 144 KB
  int bid = blockIdx.x;
  int swz = (bid & 7) * 72 + (bid >> 3);   // bijective: 576 % 8 == 0
  int oIdx = swz % 18, pIdx = swz / 18;
  int oT = oIdx * 128;
  int pG = pIdx * 256;

  v4f acc[4][4] = {};
  gemm_core(Wb + (size_t)oT * CDIM, xT + (size_t)pG * CDIM, sm, acc);

  int t = threadIdx.x, lane = t & 63, wid = t >> 6;
  int ln = lane & 15, quad = lane >> 4;
  int wm = wid >> 2, wn = wid & 3;
  bool isV = oT >= 2 * CDIM;
#pragma unroll
  for (int m = 0; m < 4; ++m) {
#pragma unroll
    for (int n = 0; n < 4; ++n) {
      int ro = oT + wm * 64 + m * 16 + quad * 4;
      int cp = pG + wn * 64 + n * 16 + ln;
      int b = cp >> 10, p = cp & 1023;
      if (!isV) {
        u32 lo = (u32)f2bf(acc[m][n][0]) | ((u32)f2bf(acc[m][n][1]) << 16);
        u32 hi = (u32)f2bf(acc[m][n][2]) | ((u32)f2bf(acc[m][n][3]) << 16);
        *(uint2*)&qkT[((size_t)b * NSEQ + p) * 1536 + ro] = uint2{lo, hi};
      } else {
#pragma unroll
        for (int r = 0; r < 4; ++r)
          vbuf[((size_t)b * CDIM + (ro - 2 * CDIM + r)) * NSEQ + p] =
              f2bf(acc[m][n][r]);
      }
    }
  }
}

// ------------- kernel: flash attention ----------------------------------
__global__ __launch_bounds__(256) void k_attn(const u16* __restrict__ qkT,
                                              const u16* __restrict__ vbuf,
                                              u16* __restrict__ attnT) {
  int id = blockIdx.x;
  int b = id & 7;
  int j = id >> 3;
  int h = j % 12;
  int nt0 = (j / 12) * 128;

  int t = threadIdx.x, lane = t & 63, wid = t >> 6;
  int ln = lane & 15, quad = lane >> 4;
  int nbase = nt0 + wid * 32;

  __shared__ u16 Ks[2][2][64 * 32];
  __shared__ u16 Vs[2][2][64 * 32];
  __shared__ u16 Pa[4][32 * 72];
  u16* myP = Pa[wid];

  const u16* qbase = qkT + ((size_t)b * NSEQ + nbase) * 1536 + h * DH;
  bf16x8 aq[2][2];
#pragma unroll
  for (int mt = 0; mt < 2; ++mt)
#pragma unroll
    for (int ks = 0; ks < 2; ++ks)
      aq[mt][ks] = *(const bf16x8*)&qbase[(size_t)(mt * 16 + ln) * 1536 + ks * 32 + quad * 8];

  bf16x8 ones;
#pragma unroll
  for (int i = 0; i < 8; ++i) ones[i] = __builtin_bit_cast(__bf16, (u16)0x3F80);

  v4f oacc[2][4] = {};
  v4f lacc[2] = {};

  int lr = lane >> 2, lc = (lane & 3) * 8;
  const u16* kgw = qkT + (size_t)b * NSEQ * 1536 + CDIM + h * DH +
                   (size_t)(wid * 16 + lr) * 1536 + lc;
  const u16* vgw = vbuf + ((size_t)b * CDIM + h * DH + wid * 16 + lr) * NSEQ + lc;
  int sb = (wid * 16) * 32;

  gload16(kgw, &Ks[0][0][sb]);
  gload16(kgw + 32, &Ks[0][1][sb]);
  gload16(vgw, &Vs[0][0][sb]);
  gload16(vgw + 32, &Vs[0][1][sb]);
  __syncthreads();

  for (int s = 0; s < 16; ++s) {
    int cur = s & 1, nxt = cur ^ 1;
    if (s < 15) {
      size_t ko = (size_t)(s + 1) * 64 * 1536;
      int vo = (s + 1) * 64;
      gload16(kgw + ko, &Ks[nxt][0][sb]);
      gload16(kgw + ko + 32, &Ks[nxt][1][sb]);
      gload16(vgw + vo, &Vs[nxt][0][sb]);
      gload16(vgw + vo + 32, &Vs[nxt][1][sb]);
    }

#pragma unroll
    for (int ct = 0; ct < 4; ++ct) {
      bf16x8 kf0 = *(const bf16x8*)&Ks[cur][0][(ct * 16 + ln) * 32 + quad * 8];
      bf16x8 kf1 = *(const bf16x8*)&Ks[cur][1][(ct * 16 + ln) * 32 + quad * 8];
#pragma unroll
      for (int mt = 0; mt < 2; ++mt) {
        v4f sc = {};
        sc = mfma16(kf0, aq[mt][0], sc);
        sc = mfma16(kf1, aq[mt][1], sc);
        float p0 = __builtin_amdgcn_exp2f(sc[0] * SCL);
        float p1 = __builtin_amdgcn_exp2f(sc[1] * SCL);
        float p2 = __builtin_amdgcn_exp2f(sc[2] * SCL);
        float p3 = __builtin_amdgcn_exp2f(sc[3] * SCL);
        *(uint2*)&myP[(mt * 16 + ln) * 72 + ct * 16 + quad * 4] =
            uint2{pkbf(p1, p0), pkbf(p3, p2)};
      }
    }

    bf16x8 ap[2][2];
#pragma unroll
    for (int mt = 0; mt < 2; ++mt)
#pragma unroll
      for (int ks = 0; ks < 2; ++ks)
        ap[mt][ks] = *(const bf16x8*)&myP[(mt * 16 + ln) * 72 + ks * 32 + quad * 8];
#pragma unroll
    for (int mt = 0; mt < 2; ++mt) {
      lacc[mt] = mfma16(ap[mt][0], ones, lacc[mt]);
      lacc[mt] = mfma16(ap[mt][1], ones, lacc[mt]);
    }
#pragma unroll
    for (int nt = 0; nt < 4; ++nt) {
      bf16x8 vf0 = *(const bf16x8*)&Vs[cur][0][(nt * 16 + ln) * 32 + quad * 8];
      bf16x8 vf1 = *(const bf16x8*)&Vs[cur][1][(nt * 16 + ln) * 32 + quad * 8];
#pragma unroll
      for (int mt = 0; mt < 2; ++mt) {
        oacc[mt][nt] = mfma16(ap[mt][0], vf0, oacc[mt][nt]);
        oacc[mt][nt] = mfma16(ap[mt][1], vf1, oacc[mt][nt]);
      }
    }
    __syncthreads();
  }

#pragma unroll
  for (int mt = 0; mt < 2; ++mt) {
#pragma unroll
    for (int r = 0; r < 4; ++r) {
      float inv = 1.0f / lacc[mt][r];
      int n = nbase + mt * 16 + quad * 4 + r;
      u16* dst = attnT + ((size_t)b * NSEQ + n) * CDIM + h * DH;
#pragma unroll
      for (int nt = 0; nt < 4; ++nt)
        dst[nt * 16 + ln] = b16(oacc[mt][nt][r] * inv);
    }
  }
}

// ------------- kernel: proj GEMM ----------------------------------------
__global__ __launch_bounds__(512, 2) void k_gemm_proj(const u16* __restrict__ Wb,
                                                      const u16* __restrict__ aT,
                                                      float* __restrict__ out) {
  __shared__ u16 sm[3 * 24576];   // 144 KB
  int bid = blockIdx.x;
  int swz = (bid & 7) * 24 + (bid >> 3);   // bijective: 192 % 8 == 0
  int oIdx = swz % 6, pIdx = swz / 6;
  int oT = oIdx * 128;
  int pG = pIdx * 256;

  v4f acc[4][4] = {};
  gemm_core(Wb + (size_t)oT * CDIM, aT + (size_t)pG * CDIM, sm, acc);

  int t = threadIdx.x, lane = t & 63, wid = t >> 6;
  int ln = lane & 15, quad = lane >> 4;
  int wm = wid >> 2, wn = wid & 3;
#pragma unroll
  for (int m = 0; m < 4; ++m) {
#pragma unroll
    for (int n = 0; n < 4; ++n) {
      int ro = oT + wm * 64 + m * 16 + quad * 4;
      int cp = pG + wn * 64 + n * 16 + ln;
      int b = cp >> 10, p = cp & 1023;
#pragma unroll
      for (int r = 0; r < 4; ++r)
        out[((size_t)b * CDIM + ro + r) * NSEQ + p] = acc[m][n][r];
    }
  }
}

extern "C" void kernel_launch(void* const* d_in, const int* in_sizes, int n_in,
                              void* d_out, int out_size, void* d_ws, size_t ws_size,
                              hipStream_t stream) {
  const float* x = (const float*)d_in[0];
  const float* w_qkv = (const float*)d_in[1];
  const float* w_proj = (const float*)d_in[2];
  float* out = (float*)d_out;

  char* ws = (char*)d_ws;
  u16* wqkv_bf = (u16*)(ws);
  u16* wproj_bf = (u16*)(ws + 3538944);
  u16* xT = (u16*)(ws + 4718592);
  u16* vbuf = (u16*)(ws + 17301504);
  u16* qkT = (u16*)d_out;
  u16* attnT = xT;

  k_prep<<<dim3(3840), dim3(256), 0, stream>>>(x, w_qkv, w_proj, xT, wqkv_bf, wproj_bf);
  k_gemm_qkv<<<dim3(576), dim3(512), 0, stream>>>(wqkv_bf, xT, qkT, vbuf);
  k_attn<<<dim3(768), dim3(256), 0, stream>>>(qkT, vbuf, attnT);
  k_gemm_proj<<<dim3(192), dim3(512), 0, stream>>>(wproj_bf, attnT, out);
}

// Round 4
// 184.582 us; speedup vs baseline: 1.0458x; 1.0337x over previous
//
#include <hip/hip_runtime.h>

typedef unsigned short u16;
typedef unsigned int u32;
typedef float v4f __attribute__((ext_vector_type(4)));
typedef __bf16 bf16x8 __attribute__((ext_vector_type(8)));

#define BATCH 8
#define CDIM 768
#define NHEAD 12
#define DH 64
#define NSEQ 1024
#define SCL 0.18033688011112042f

__device__ __forceinline__ u16 f2bf(float f) {
  u32 u = __builtin_bit_cast(u32, f);
  u += 0x7fffu + ((u >> 16) & 1u);   // RNE
  return (u16)(u >> 16);
}

__device__ __forceinline__ u16 b16(float f) {
  return (u16)((__builtin_bit_cast(u32, f) + 0x8000u) >> 16);
}

__device__ __forceinline__ u32 pkbf(float hi, float lo) {
  u32 a = __builtin_bit_cast(u32, hi) + 0x8000u;
  u32 b = __builtin_bit_cast(u32, lo) + 0x8000u;
  return __builtin_amdgcn_perm(a, b, 0x07060302u);  // {a[31:16], b[31:16]}
}

__device__ __forceinline__ v4f mfma16(bf16x8 a, bf16x8 b, v4f c) {
  return __builtin_amdgcn_mfma_f32_16x16x32_bf16(a, b, c, 0, 0, 0);
}

__device__ __forceinline__ void gload16(const u16* g, u16* l) {
  __builtin_amdgcn_global_load_lds(
      (const __attribute__((address_space(1))) void*)g,
      (__attribute__((address_space(3))) void*)l, 16, 0, 0);
}

// ------------- kernel: fused prep --------------------------------------
__global__ __launch_bounds__(256) void k_prep(const float* __restrict__ x,
                                              const float* __restrict__ wq,
                                              const float* __restrict__ wp,
                                              u16* __restrict__ xT,
                                              u16* __restrict__ wqb,
                                              u16* __restrict__ wpb) {
  __shared__ u16 Ts[64][72];
  int bid = blockIdx.x;
  int t = threadIdx.x;
  if (bid < 2304) {
    bool isQ = bid < 1728;
    const float* s = isQ ? wq : wp;
    u16* d = isQ ? wqb : wpb;
    int i = (isQ ? bid : bid - 1728) * 256 + t;
    float4 v = ((const float4*)s)[i];
    u32 lo = (u32)f2bf(v.x) | ((u32)f2bf(v.y) << 16);
    u32 hi = (u32)f2bf(v.z) | ((u32)f2bf(v.w) << 16);
    ((uint2*)d)[i] = uint2{lo, hi};
    return;
  }
  int id = bid - 2304;
  int p0 = (id & 15) * 64; id >>= 4;
  int c0 = (id % 12) * 64; int b = id / 12;
  int cr = t >> 4;
  int p4 = (t & 15) * 4;
  const float* src = x + ((size_t)b * CDIM + c0) * NSEQ + p0;
#pragma unroll
  for (int i = 0; i < 4; ++i) {
    int c = cr + i * 16;
    float4 v = *(const float4*)&src[(size_t)c * NSEQ + p4];
    Ts[p4 + 0][c] = f2bf(v.x);
    Ts[p4 + 1][c] = f2bf(v.y);
    Ts[p4 + 2][c] = f2bf(v.z);
    Ts[p4 + 3][c] = f2bf(v.w);
  }
  __syncthreads();
  int p = t >> 2;
  int cq = t & 3;
  u16* dst = xT + ((size_t)b * NSEQ + p0 + p) * CDIM + c0;
#pragma unroll
  for (int j = 0; j < 2; ++j) {
    int ch = cq + j * 4;
    *(int4*)&dst[ch * 8] = *(const int4*)&Ts[p][ch * 8];
  }
}

// ------------- 256x128 pipelined GEMM core (BK=32, 2 blocks/CU) ---------
// 256 thr / 4 waves (2M x 2N), per-wave 128x64 output -> 0.375 ds_reads
// per MFMA (A-frags reused across phases' B... B-frags reused across all
// 8 m-frags). LDS: 3 bufs x (A 256x32 + B 128x32) bf16 = 72 KB -> 2
// blocks/CU for cross-block latency hiding. Chunk-XOR swizzle with
// (row>>1)&3 (4-chunk/64B rows): read banks land 2-way (free), staged via
// pre-swizzled global source (LDS dest linear, as global_load_lds needs).
// Pipeline: compute kt while staging kt+2; 6 DMA instrs/tile; vmcnt(6)
// drains exactly tile kt+1's group each iteration (never 0 mid-loop).
#define NKT 24     // CDIM/32

__device__ __forceinline__ void gemm_core(const u16* __restrict__ Ag,
                                          const u16* __restrict__ Bg,
                                          u16* sm, v4f (&acc)[8][4]) {
  int t = threadIdx.x, lane = t & 63, wid = t >> 6;
  int ln = lane & 15, quad = lane >> 4;
  int wm = wid >> 1, wn = wid & 1;

  // staging: per gload16 each wave covers 16 rows (4 lanes/row, 4 chunks).
  // stored chunk slot (l&3) sources global chunk (l&3)^((l>>3)&3)
  // [= (l&3)^((row>>1)&3) since row = slab + wid*16 + (l>>2)].
  int srow = wid * 16 + (lane >> 2);
  int scg = ((lane & 3) ^ ((lane >> 3) & 3)) * 8;
  const u16* As0 = Ag + (size_t)srow * CDIM + scg;
  const u16* Bs0 = Bg + (size_t)srow * CDIM + scg;
  int ldw = wid * 512;   // u16, wave offset inside a 2048-u16 (64-row) slab

  // fragment reads: global chunk quad at row r lives in slot quad^((r>>1)&3)
  int cA = (quad ^ ((ln >> 1) & 3)) * 8;
  int rA = (wm * 128 + ln) * 32;            // A region base (u16)
  int rB = 8192 + (wn * 64 + ln) * 32;      // B region at 8192

  // ---- prologue: stage K-tiles 0 and 1 (6 instrs each, order-fenced) ----
  {
    u16* sb0 = sm;
    gload16(As0, sb0 + ldw);
    gload16(As0 + (size_t)64 * CDIM, sb0 + 2048 + ldw);
    gload16(As0 + (size_t)128 * CDIM, sb0 + 4096 + ldw);
    gload16(As0 + (size_t)192 * CDIM, sb0 + 6144 + ldw);
    gload16(Bs0, sb0 + 8192 + ldw);
    gload16(Bs0 + (size_t)64 * CDIM, sb0 + 10240 + ldw);
  }
  asm volatile("" ::: "memory");   // keep group 0 older than group 1 (vmcnt)
  {
    u16* sb1 = sm + 12288;
    gload16(As0 + 32, sb1 + ldw);
    gload16(As0 + (size_t)64 * CDIM + 32, sb1 + 2048 + ldw);
    gload16(As0 + (size_t)128 * CDIM + 32, sb1 + 4096 + ldw);
    gload16(As0 + (size_t)192 * CDIM + 32, sb1 + 6144 + ldw);
    gload16(Bs0 + 32, sb1 + 8192 + ldw);
    gload16(Bs0 + (size_t)64 * CDIM + 32, sb1 + 10240 + ldw);
  }
  asm volatile("s_waitcnt vmcnt(6)" ::: "memory");   // tile 0 resident
  asm volatile("s_barrier" ::: "memory");

  for (int kb = 0; kb < 8; ++kb) {
#pragma unroll
    for (int u = 0; u < 3; ++u) {
      int kt = kb * 3 + u;
      const u16* sb = sm + u * 12288;              // kt%3 == u
      u16* nb = sm + ((u + 2) % 3) * 12288;        // stage target (kt+2)
      int ko = (kt + 2) * 32;

      // ---- phase 0: read A m0-3 + all B; stage 3 of 6; MFMA m0-3 ----
      bf16x8 af[4], bfr[4];
#pragma unroll
      for (int m = 0; m < 4; ++m)
        af[m] = *(const bf16x8*)&sb[rA + m * 512 + cA];
#pragma unroll
      for (int n = 0; n < 4; ++n)
        bfr[n] = *(const bf16x8*)&sb[rB + n * 512 + cA];
      if (kt < NKT - 2) {
        gload16(As0 + ko, nb + ldw);
        gload16(As0 + (size_t)64 * CDIM + ko, nb + 2048 + ldw);
        gload16(Bs0 + ko, nb + 8192 + ldw);
      }
      asm volatile("s_barrier" ::: "memory");
      asm volatile("s_waitcnt lgkmcnt(0)" ::: "memory");
      __builtin_amdgcn_sched_barrier(0);
      __builtin_amdgcn_s_setprio(1);
#pragma unroll
      for (int m = 0; m < 4; ++m)
#pragma unroll
        for (int n = 0; n < 4; ++n)
          acc[m][n] = mfma16(af[m], bfr[n], acc[m][n]);
      __builtin_amdgcn_s_setprio(0);
      asm volatile("s_barrier" ::: "memory");

      // ---- phase 1: read A m4-7 (B reused); stage 3; vmcnt; MFMA ----
#pragma unroll
      for (int m = 0; m < 4; ++m)
        af[m] = *(const bf16x8*)&sb[rA + (m + 4) * 512 + cA];
      if (kt < NKT - 2) {
        gload16(As0 + (size_t)128 * CDIM + ko, nb + 4096 + ldw);
        gload16(As0 + (size_t)192 * CDIM + ko, nb + 6144 + ldw);
        gload16(Bs0 + (size_t)64 * CDIM + ko, nb + 10240 + ldw);
        // drain tile kt+1's 6 (oldest), leave kt+2's 6 in flight
        asm volatile("s_waitcnt vmcnt(6)" ::: "memory");
      } else if (kt == NKT - 2) {
        asm volatile("s_waitcnt vmcnt(0)" ::: "memory");   // tail drain
      }
      asm volatile("s_barrier" ::: "memory");
      asm volatile("s_waitcnt lgkmcnt(0)" ::: "memory");
      __builtin_amdgcn_sched_barrier(0);
      __builtin_amdgcn_s_setprio(1);
#pragma unroll
      for (int m = 0; m < 4; ++m)
#pragma unroll
        for (int n = 0; n < 4; ++n)
          acc[m + 4][n] = mfma16(af[m], bfr[n], acc[m + 4][n]);
      __builtin_amdgcn_s_setprio(0);
      asm volatile("s_barrier" ::: "memory");
    }
  }
}

// ------------- kernel: QKV GEMM  D[o][p] = sum_c W[o][c] * xT[p][c] -----
// 576 blocks (9 oT x 64 p-panels) at 2 blocks/CU. XCD swizzle: XCD x gets
// swz in [72x,72x+72) -> pIdx in [8x,8x+8) = exactly batch x (1.5 MB xT
// L2-resident) x all 9 o-tiles.
__global__ __launch_bounds__(256, 2) void k_gemm_qkv(const u16* __restrict__ Wb,
                                                     const u16* __restrict__ xT,
                                                     u16* __restrict__ qkT,
                                                     u16* __restrict__ vbuf) {
  __shared__ u16 sm[3 * 12288];   // 72 KB
  int bid = blockIdx.x;
  int swz = (bid & 7) * 72 + (bid >> 3);   // bijective: 576 % 8 == 0
  int oIdx = swz % 9, pIdx = swz / 9;
  int oT = oIdx * 256;
  int pG = pIdx * 128;                     // global p row (b*1024 + p)

  v4f acc[8][4] = {};
  gemm_core(Wb + (size_t)oT * CDIM, xT + (size_t)pG * CDIM, sm, acc);

  int t = threadIdx.x, lane = t & 63, wid = t >> 6;
  int ln = lane & 15, quad = lane >> 4;
  int wm = wid >> 1, wn = wid & 1;
  bool isV = oT >= 2 * CDIM;               // oIdx 6,7,8
#pragma unroll
  for (int m = 0; m < 8; ++m) {
#pragma unroll
    for (int n = 0; n < 4; ++n) {
      int ro = oT + wm * 128 + m * 16 + quad * 4;   // 4 consecutive o rows
      int cp = pG + wn * 64 + n * 16 + ln;
      int b = cp >> 10, p = cp & 1023;
      if (!isV) {
        u32 lo = (u32)f2bf(acc[m][n][0]) | ((u32)f2bf(acc[m][n][1]) << 16);
        u32 hi = (u32)f2bf(acc[m][n][2]) | ((u32)f2bf(acc[m][n][3]) << 16);
        *(uint2*)&qkT[((size_t)b * NSEQ + p) * 1536 + ro] = uint2{lo, hi};
      } else {
#pragma unroll
        for (int r = 0; r < 4; ++r)
          vbuf[((size_t)b * CDIM + (ro - 2 * CDIM + r)) * NSEQ + p] =
              f2bf(acc[m][n][r]);
      }
    }
  }
}

// ------------- kernel: flash attention ----------------------------------
// K/V slabs now [64 rows][64 cols] (128 B pitch = all 32 banks) with
// 8-chunk XOR swizzle (slot c holds data chunk c^(row&7)) via pre-swizzled
// global source -> ds_read_b128 lands 2-way (free) vs old 8-way.
__global__ __launch_bounds__(256) void k_attn(const u16* __restrict__ qkT,
                                              const u16* __restrict__ vbuf,
                                              u16* __restrict__ attnT) {
  int id = blockIdx.x;
  int b = id & 7;
  int j = id >> 3;
  int h = j % 12;
  int nt0 = (j / 12) * 128;

  int t = threadIdx.x, lane = t & 63, wid = t >> 6;
  int ln = lane & 15, quad = lane >> 4;
  int nbase = nt0 + wid * 32;

  __shared__ u16 Ks[2][64 * 64];   // [buf][key][feat-chunk swizzled] 8 KB
  __shared__ u16 Vs[2][64 * 64];   // [buf][d][key-chunk swizzled]
  __shared__ u16 Pa[4][32 * 72];
  u16* myP = Pa[wid];

  const u16* qbase = qkT + ((size_t)b * NSEQ + nbase) * 1536 + h * DH;
  bf16x8 aq[2][2];
#pragma unroll
  for (int mt = 0; mt < 2; ++mt)
#pragma unroll
    for (int ks = 0; ks < 2; ++ks)
      aq[mt][ks] = *(const bf16x8*)&qbase[(size_t)(mt * 16 + ln) * 1536 + ks * 32 + quad * 8];

  bf16x8 ones;
#pragma unroll
  for (int i = 0; i < 8; ++i) ones[i] = __builtin_bit_cast(__bf16, (u16)0x3F80);

  v4f oacc[2][4] = {};
  v4f lacc[2] = {};

  // staging: per gload16 a wave covers 8 rows x 8 chunks; slot (l&7)
  // sources chunk (l&7)^(l>>3) [row&7 == l>>3].
  int sr8 = lane >> 3;
  int sch = ((lane & 7) ^ sr8) * 8;
  const u16* kg0 = qkT + ((size_t)b * NSEQ + wid * 16 + sr8) * 1536 + CDIM + h * DH + sch;
  const u16* vg0 = vbuf + ((size_t)b * CDIM + h * DH + wid * 16 + sr8) * NSEQ + sch;
  int sK = (wid * 16) * 64;   // wave-uniform LDS base (u16)

  // read-side swizzled chunk slots
  int sw0 = (quad ^ (ln & 7)) * 8;          // data chunks 0..3  (k 0..31)
  int sw1 = ((4 + quad) ^ (ln & 7)) * 8;    // data chunks 4..7  (k 32..63)

  // prologue: slab 0 -> buf 0, drain
  gload16(kg0, &Ks[0][sK]);
  gload16(kg0 + (size_t)8 * 1536, &Ks[0][sK + 512]);
  gload16(vg0, &Vs[0][sK]);
  gload16(vg0 + 8 * NSEQ, &Vs[0][sK + 512]);
  __syncthreads();

  for (int s = 0; s < 16; ++s) {
    int cur = s & 1, nxt = cur ^ 1;
    if (s < 15) {
      size_t ko = (size_t)(s + 1) * 64 * 1536;
      int vo = (s + 1) * 64;
      gload16(kg0 + ko, &Ks[nxt][sK]);
      gload16(kg0 + ko + (size_t)8 * 1536, &Ks[nxt][sK + 512]);
      gload16(vg0 + vo, &Vs[nxt][sK]);
      gload16(vg0 + vo + 8 * NSEQ, &Vs[nxt][sK + 512]);
    }

#pragma unroll
    for (int ct = 0; ct < 4; ++ct) {
      bf16x8 kf0 = *(const bf16x8*)&Ks[cur][(ct * 16 + ln) * 64 + sw0];
      bf16x8 kf1 = *(const bf16x8*)&Ks[cur][(ct * 16 + ln) * 64 + sw1];
#pragma unroll
      for (int mt = 0; mt < 2; ++mt) {
        v4f sc = {};
        sc = mfma16(kf0, aq[mt][0], sc);
        sc = mfma16(kf1, aq[mt][1], sc);
        float p0 = __builtin_amdgcn_exp2f(sc[0] * SCL);
        float p1 = __builtin_amdgcn_exp2f(sc[1] * SCL);
        float p2 = __builtin_amdgcn_exp2f(sc[2] * SCL);
        float p3 = __builtin_amdgcn_exp2f(sc[3] * SCL);
        *(uint2*)&myP[(mt * 16 + ln) * 72 + ct * 16 + quad * 4] =
            uint2{pkbf(p1, p0), pkbf(p3, p2)};
      }
    }

    bf16x8 ap[2][2];
#pragma unroll
    for (int mt = 0; mt < 2; ++mt)
#pragma unroll
      for (int ks = 0; ks < 2; ++ks)
        ap[mt][ks] = *(const bf16x8*)&myP[(mt * 16 + ln) * 72 + ks * 32 + quad * 8];
#pragma unroll
    for (int mt = 0; mt < 2; ++mt) {
      lacc[mt] = mfma16(ap[mt][0], ones, lacc[mt]);
      lacc[mt] = mfma16(ap[mt][1], ones, lacc[mt]);
    }
#pragma unroll
    for (int nt = 0; nt < 4; ++nt) {
      bf16x8 vf0 = *(const bf16x8*)&Vs[cur][(nt * 16 + ln) * 64 + sw0];
      bf16x8 vf1 = *(const bf16x8*)&Vs[cur][(nt * 16 + ln) * 64 + sw1];
#pragma unroll
      for (int mt = 0; mt < 2; ++mt) {
        oacc[mt][nt] = mfma16(ap[mt][0], vf0, oacc[mt][nt]);
        oacc[mt][nt] = mfma16(ap[mt][1], vf1, oacc[mt][nt]);
      }
    }
    __syncthreads();
  }

#pragma unroll
  for (int mt = 0; mt < 2; ++mt) {
#pragma unroll
    for (int r = 0; r < 4; ++r) {
      float inv = 1.0f / lacc[mt][r];
      int n = nbase + mt * 16 + quad * 4 + r;
      u16* dst = attnT + ((size_t)b * NSEQ + n) * CDIM + h * DH;
#pragma unroll
      for (int nt = 0; nt < 4; ++nt)
        dst[nt * 16 + ln] = b16(oacc[mt][nt][r] * inv);
    }
  }
}

// ------------- kernel: proj GEMM ----------------------------------------
__global__ __launch_bounds__(256, 2) void k_gemm_proj(const u16* __restrict__ Wb,
                                                      const u16* __restrict__ aT,
                                                      float* __restrict__ out) {
  __shared__ u16 sm[3 * 12288];   // 72 KB
  int bid = blockIdx.x;
  int swz = (bid & 7) * 24 + (bid >> 3);   // bijective: 192 % 8 == 0
  int oIdx = swz % 3, pIdx = swz / 3;
  int oT = oIdx * 256;
  int pG = pIdx * 128;

  v4f acc[8][4] = {};
  gemm_core(Wb + (size_t)oT * CDIM, aT + (size_t)pG * CDIM, sm, acc);

  int t = threadIdx.x, lane = t & 63, wid = t >> 6;
  int ln = lane & 15, quad = lane >> 4;
  int wm = wid >> 1, wn = wid & 1;
#pragma unroll
  for (int m = 0; m < 8; ++m) {
#pragma unroll
    for (int n = 0; n < 4; ++n) {
      int ro = oT + wm * 128 + m * 16 + quad * 4;
      int cp = pG + wn * 64 + n * 16 + ln;
      int b = cp >> 10, p = cp & 1023;
#pragma unroll
      for (int r = 0; r < 4; ++r)
        out[((size_t)b * CDIM + ro + r) * NSEQ + p] = acc[m][n][r];
    }
  }
}

extern "C" void kernel_launch(void* const* d_in, const int* in_sizes, int n_in,
                              void* d_out, int out_size, void* d_ws, size_t ws_size,
                              hipStream_t stream) {
  const float* x = (const float*)d_in[0];
  const float* w_qkv = (const float*)d_in[1];
  const float* w_proj = (const float*)d_in[2];
  float* out = (float*)d_out;

  char* ws = (char*)d_ws;
  u16* wqkv_bf = (u16*)(ws);
  u16* wproj_bf = (u16*)(ws + 3538944);
  u16* xT = (u16*)(ws + 4718592);
  u16* vbuf = (u16*)(ws + 17301504);
  u16* qkT = (u16*)d_out;
  u16* attnT = xT;

  k_prep<<<dim3(3840), dim3(256), 0, stream>>>(x, w_qkv, w_proj, xT, wqkv_bf, wproj_bf);
  k_gemm_qkv<<<dim3(576), dim3(256), 0, stream>>>(wqkv_bf, xT, qkT, vbuf);
  k_attn<<<dim3(768), dim3(256), 0, stream>>>(qkT, vbuf, attnT);
  k_gemm_proj<<<dim3(192), dim3(256), 0, stream>>>(wproj_bf, attnT, out);
}